// Round 2
// baseline (36864.850 us; speedup 1.0000x reference)
//
#include <hip/hip_runtime.h>
#include <math.h>

#define N_   4096
#define E_   128
#define H_   256
#define G4_  1024
#define SCALE_T 2.8853900817779268f   // 2*log2(e): exp2(S*x) = e^(2x)
#define NEG_BIG -1.0e30f              // finite stand-in for -inf (harness: inf-inf -> NaN)

// ---------------------------------------------------------------------------
// init: pos[i]=INF, tour tail of d_out, cnt=0, negv2[d]=-2*v[d], sumv=sum(v)
// ---------------------------------------------------------------------------
__global__ __launch_bounds__(256) void init_misc(
    const int* __restrict__ tour, const float* __restrict__ v,
    float* __restrict__ out_tail, int* __restrict__ pos,
    unsigned* __restrict__ cnt, float* __restrict__ negv2, float* __restrict__ sumv)
{
    const int i = blockIdx.x * 256 + threadIdx.x;
    if (i < N_) {
        pos[i] = 0x7FFFFFFF;
        out_tail[i] = (float)tour[i];
    }
    if (blockIdx.x == 0) {
        __shared__ float red[256];
        const float vv = v[threadIdx.x];
        negv2[threadIdx.x] = -2.f * vv;
        red[threadIdx.x] = vv;
        __syncthreads();
        for (int s = 128; s > 0; s >>= 1) {
            if (threadIdx.x < s) red[threadIdx.x] += red[threadIdx.x + s];
            __syncthreads();
        }
        if (threadIdx.x == 0) { sumv[0] = red[0]; *cnt = 0u; }
    }
}

__global__ __launch_bounds__(256) void pos_scatter(
    const int* __restrict__ tour, int* __restrict__ pos)
{
    const int i = blockIdx.x * 256 + threadIdx.x;
    if (i < N_) atomicMin(&pos[tour[i]], i);
}

// ---------------------------------------------------------------------------
// embeddings: K=2 matvec, emb = x@eW.T+eb ; city = x@cW.T+cb
// ---------------------------------------------------------------------------
__global__ __launch_bounds__(256) void embed2(
    const float* __restrict__ x,
    const float* __restrict__ eW, const float* __restrict__ eb,
    const float* __restrict__ cW, const float* __restrict__ cb,
    float* __restrict__ emb, float* __restrict__ city)
{
    const int m = blockIdx.x, tid = threadIdx.x;
    const float x0 = x[2*m], x1 = x[2*m+1];
    if (tid < E_) {
        emb[(size_t)m*E_ + tid] = x0*eW[2*tid] + x1*eW[2*tid+1] + eb[tid];
    } else {
        const int e = tid - E_;
        city[(size_t)m*E_ + e] = x0*cW[2*e] + x1*cW[2*e+1] + cb[e];
    }
}

// dec_seq[0]=start_token ; dec_seq[t]=city_embs[tour[t-1]]
__global__ __launch_bounds__(128) void gather_dec(
    const float* __restrict__ city, const float* __restrict__ st,
    const int* __restrict__ tour, float* __restrict__ dseq)
{
    const int t = blockIdx.x, e = threadIdx.x;
    dseq[(size_t)t*E_ + e] = (t == 0) ? st[e] : city[(size_t)tour[t-1]*E_ + e];
}

// ---------------------------------------------------------------------------
// generic fp32 GEMM: C[M,N] = scale*(A[M,K] @ B[N,K]^T) (+b0[n]) (+b1[n])
// storeT: write C transposed as C[n*M+m] (used for projT)
// ---------------------------------------------------------------------------
__global__ __launch_bounds__(256) void gemm64(
    const float* __restrict__ A, const float* __restrict__ B, float* __restrict__ C,
    int M, int N, int K, const float* __restrict__ b0, const float* __restrict__ b1,
    float scale, int storeT)
{
    __shared__ float As[16][68];
    __shared__ float Bs[16][68];
    const int tid = threadIdx.x;
    const int m0 = blockIdx.y * 64, n0 = blockIdx.x * 64;
    const int tx = tid & 15, ty = tid >> 4;
    const int lr = tid >> 2, lk = (tid & 3) * 4;
    float acc[4][4] = {};
    for (int kb = 0; kb < K; kb += 16) {
        const float4 a4 = *(const float4*)&A[(size_t)(m0+lr)*K + kb + lk];
        const float4 b4 = *(const float4*)&B[(size_t)(n0+lr)*K + kb + lk];
        __syncthreads();
        As[lk][lr]=a4.x; As[lk+1][lr]=a4.y; As[lk+2][lr]=a4.z; As[lk+3][lr]=a4.w;
        Bs[lk][lr]=b4.x; Bs[lk+1][lr]=b4.y; Bs[lk+2][lr]=b4.z; Bs[lk+3][lr]=b4.w;
        __syncthreads();
        #pragma unroll
        for (int k = 0; k < 16; ++k) {
            const float4 av4 = *(const float4*)&As[k][ty*4];
            const float4 bv4 = *(const float4*)&Bs[k][tx*4];
            const float avv[4] = {av4.x, av4.y, av4.z, av4.w};
            const float bvv[4] = {bv4.x, bv4.y, bv4.z, bv4.w};
            #pragma unroll
            for (int i = 0; i < 4; ++i)
                #pragma unroll
                for (int j = 0; j < 4; ++j)
                    acc[i][j] += avv[i] * bvv[j];
        }
    }
    #pragma unroll
    for (int i = 0; i < 4; ++i) {
        const int m = m0 + ty*4 + i;
        #pragma unroll
        for (int j = 0; j < 4; ++j) {
            const int n = n0 + tx*4 + j;
            float val = scale * acc[i][j];
            if (b0) val += b0[n];
            if (b1) val += b1[n];
            if (storeT) C[(size_t)n*M + m] = val;
            else        C[(size_t)m*N + n] = val;
        }
    }
}

// ---------------------------------------------------------------------------
// LSTM scan: 4 WGs x 256 thr. Thread owns gate row (q*256 + g*64 + l) with its
// 256 fp32 Whh weights register-resident. h exchanged via double-buffered
// global hglob[2][256] (agent-scope atomics) + release/acquire step counter.
// ---------------------------------------------------------------------------
__device__ __forceinline__ void load_w(const float* __restrict__ whh, int row, float (&w)[256])
{
    #pragma unroll
    for (int k = 0; k < 256; k += 4) {
        const float4 f = *(const float4*)&whh[(size_t)row*256 + k];
        w[k] = f.x; w[k+1] = f.y; w[k+2] = f.z; w[k+3] = f.w;
    }
}

__device__ __forceinline__ void scan_phase(
    const float* __restrict__ xih, const float (&w)[256], float* __restrict__ outbuf,
    int u0, float& c_loc, float* __restrict__ hglob, unsigned* __restrict__ cnt,
    float* __restrict__ hs, float* __restrict__ act,
    int tid, int q, int l, int g, int row)
{
    for (int s = 0; s < N_; ++s) {
        const int ustep = u0 + s;
        const float xv = xih[(size_t)s*G4_ + row];   // prefetch; biases pre-folded
        if (tid == 0) {
            const unsigned target = 4u * (unsigned)(ustep + 1);
            while (__hip_atomic_load(cnt, __ATOMIC_ACQUIRE, __HIP_MEMORY_SCOPE_AGENT) < target)
                __builtin_amdgcn_s_sleep(1);
        }
        __syncthreads();
        hs[tid] = __hip_atomic_load(&hglob[(ustep & 1)*256 + tid],
                                    __ATOMIC_RELAXED, __HIP_MEMORY_SCOPE_AGENT);
        __syncthreads();
        float a0 = xv, a1 = 0.f, a2 = 0.f, a3 = 0.f;
        #pragma unroll
        for (int k = 0; k < 256; k += 4) {
            const float4 hv = *(const float4*)&hs[k];
            a0 += w[k]   * hv.x;
            a1 += w[k+1] * hv.y;
            a2 += w[k+2] * hv.z;
            a3 += w[k+3] * hv.w;
        }
        const float gate = (a0 + a1) + (a2 + a3);
        const float act_v = (q == 2) ? tanhf(gate) : 1.f/(1.f + expf(-gate));
        act[tid] = act_v;
        __syncthreads();
        if (q == 0) {
            const float iv = act[l], fv = act[64+l], gv = act[128+l], ov = act[192+l];
            c_loc = fv * c_loc + iv * gv;
            const float hn = ov * tanhf(c_loc);
            __hip_atomic_store(&hglob[((ustep+1) & 1)*256 + g*64 + l], hn,
                               __ATOMIC_RELAXED, __HIP_MEMORY_SCOPE_AGENT);
            outbuf[(size_t)s*H_ + g*64 + l] = hn;
        }
        __threadfence();
        __syncthreads();
        if (tid == 0)
            __hip_atomic_fetch_add(cnt, 1u, __ATOMIC_RELEASE, __HIP_MEMORY_SCOPE_AGENT);
    }
}

__global__ __launch_bounds__(256, 1) void lstm_scan(
    const float* __restrict__ exih, const float* __restrict__ ewhh,
    const float* __restrict__ dxih, const float* __restrict__ dwhh,
    float* __restrict__ encout, float* __restrict__ hx,
    float* __restrict__ hglob, unsigned* __restrict__ cnt)
{
    __shared__ __align__(16) float hs[256];
    __shared__ float act[256];
    const int g = blockIdx.x, tid = threadIdx.x;
    const int q = tid >> 6, l = tid & 63;
    const int row = q*256 + g*64 + l;
    float w[256];
    load_w(ewhh, row, w);
    float c_loc = 0.f;
    if (tid < 64)
        __hip_atomic_store(&hglob[g*64 + tid], 0.f, __ATOMIC_RELAXED, __HIP_MEMORY_SCOPE_AGENT);
    __threadfence();
    __syncthreads();
    if (tid == 0)
        __hip_atomic_fetch_add(cnt, 1u, __ATOMIC_RELEASE, __HIP_MEMORY_SCOPE_AGENT);
    scan_phase(exih, w, encout, 0,   c_loc, hglob, cnt, hs, act, tid, q, l, g, row);
    load_w(dwhh, row, w);
    scan_phase(dxih, w, hx,     N_,  c_loc, hglob, cnt, hs, act, tid, q, l, g, row);
}

// ---------------------------------------------------------------------------
// attention scores: e[t][i] = sumv + sum_d negv2[d] * rcp(1 + exp2(p'+u'))
// (p', u' pre-scaled by 2*log2(e), so this is sum_d v_d * tanh(p+u))
// tile: 16 t x 32 i, block-skip when all i masked for whole tile
// ---------------------------------------------------------------------------
#define TI_ 32
#define TT_ 16

__global__ __launch_bounds__(256) void attn_scores(
    const float* __restrict__ projT, const float* __restrict__ Umat,
    const float* __restrict__ negv2, const float* __restrict__ sumvp,
    const int* __restrict__ pos, float* __restrict__ out)
{
    const int i0 = blockIdx.x * TI_, t0 = blockIdx.y * TT_;
    const int tid = threadIdx.x;
    const int lane = tid & 63, wv = tid >> 6;
    const int il = lane & 31, th = lane >> 5;
    const int pi = pos[i0 + il];
    if (__all(pi < t0)) {                   // entire tile masked -> NEG_BIG
        for (int idx = tid; idx < TT_*TI_; idx += 256) {
            const int r = idx >> 5, c = idx & 31;
            out[(size_t)(t0 + r)*N_ + i0 + c] = NEG_BIG;
        }
        return;
    }
    __shared__ float pTs[256][33];
    __shared__ float Us[TT_][256];
    __shared__ float vsh[256];
    vsh[tid] = negv2[tid];
    #pragma unroll
    for (int dd = 0; dd < 8; ++dd) {
        const int d = (tid >> 3) + dd*32;
        const float4 p4 = *(const float4*)&projT[(size_t)d*N_ + i0 + (tid & 7)*4];
        const int c = (tid & 7)*4;
        pTs[d][c] = p4.x; pTs[d][c+1] = p4.y; pTs[d][c+2] = p4.z; pTs[d][c+3] = p4.w;
    }
    for (int idx = tid; idx < TT_*256; idx += 256) {
        const int r = idx >> 8, c = idx & 255;
        Us[r][c] = Umat[(size_t)(t0 + r)*H_ + c];
    }
    __syncthreads();
    const float sumv = sumvp[0];
    #pragma unroll
    for (int pass = 0; pass < 2; ++pass) {
        const int tl = pass*8 + wv*2 + th;
        const int t = t0 + tl;
        float a0 = 0.f, a1 = 0.f, a2 = 0.f, a3 = 0.f;
        #pragma unroll 8
        for (int d = 0; d < 256; d += 4) {
            const float x0 = pTs[d  ][il] + Us[tl][d  ];
            const float x1 = pTs[d+1][il] + Us[tl][d+1];
            const float x2 = pTs[d+2][il] + Us[tl][d+2];
            const float x3 = pTs[d+3][il] + Us[tl][d+3];
            a0 += vsh[d  ] * __builtin_amdgcn_rcpf(1.f + exp2f(x0));
            a1 += vsh[d+1] * __builtin_amdgcn_rcpf(1.f + exp2f(x1));
            a2 += vsh[d+2] * __builtin_amdgcn_rcpf(1.f + exp2f(x2));
            a3 += vsh[d+3] * __builtin_amdgcn_rcpf(1.f + exp2f(x3));
        }
        float val = sumv + ((a0 + a1) + (a2 + a3));
        if (pi < t) val = NEG_BIG;
        out[(size_t)t*N_ + i0 + il] = val;
    }
}

// in-place row log_softmax over d_out rows (4096 elems each)
// masked entries are NEG_BIG; NEG_BIG - lse stays NEG_BIG (fp32), exp(NEG_BIG-m)=0
__global__ __launch_bounds__(256) void logsm(float* __restrict__ out)
{
    const int t = blockIdx.x, tid = threadIdx.x;
    float* row = out + (size_t)t*N_;
    float v[16];
    float lmax = NEG_BIG;
    #pragma unroll
    for (int j = 0; j < 16; ++j) { v[j] = row[tid + j*256]; lmax = fmaxf(lmax, v[j]); }
    __shared__ float red[256];
    red[tid] = lmax; __syncthreads();
    for (int s = 128; s > 0; s >>= 1) {
        if (tid < s) red[tid] = fmaxf(red[tid], red[tid + s]);
        __syncthreads();
    }
    const float m = red[0];
    __syncthreads();
    float lsum = 0.f;
    #pragma unroll
    for (int j = 0; j < 16; ++j) lsum += __expf(v[j] - m);
    red[tid] = lsum; __syncthreads();
    for (int s = 128; s > 0; s >>= 1) {
        if (tid < s) red[tid] += red[tid + s];
        __syncthreads();
    }
    const float lse = m + logf(red[0]);
    #pragma unroll
    for (int j = 0; j < 16; ++j) row[tid + j*256] = v[j] - lse;
}

// ---------------------------------------------------------------------------
extern "C" void kernel_launch(void* const* d_in, const int* in_sizes, int n_in,
                              void* d_out, int out_size, void* d_ws, size_t ws_size,
                              hipStream_t stream)
{
    const float* x        = (const float*)d_in[0];
    const int*   tour     = (const int*)  d_in[1];
    const float* eW       = (const float*)d_in[2];
    const float* eb       = (const float*)d_in[3];
    const float* enc_Wih  = (const float*)d_in[4];
    const float* enc_Whh  = (const float*)d_in[5];
    const float* enc_bih  = (const float*)d_in[6];
    const float* enc_bhh  = (const float*)d_in[7];
    const float* dec_Wih  = (const float*)d_in[8];
    const float* dec_Whh  = (const float*)d_in[9];
    const float* dec_bih  = (const float*)d_in[10];
    const float* dec_bhh  = (const float*)d_in[11];
    const float* W1       = (const float*)d_in[12];
    const float* W2       = (const float*)d_in[13];
    const float* attv     = (const float*)d_in[14];
    const float* cW       = (const float*)d_in[15];
    const float* cb       = (const float*)d_in[16];
    const float* st       = (const float*)d_in[17];
    float* out = (float*)d_out;

    float* ws = (float*)d_ws;
    size_t o = 0;
    float* emb    = ws + o; o += (size_t)N_*E_;
    float* city   = ws + o; o += (size_t)N_*E_;
    float* dseq   = ws + o; o += (size_t)N_*E_;
    float* exih   = ws + o; o += (size_t)N_*G4_;
    float* dxih   = ws + o; o += (size_t)N_*G4_;
    float* encout = ws + o; o += (size_t)N_*H_;
    float* hx     = ws + o; o += (size_t)N_*H_;
    float* projT  = ws + o; o += (size_t)N_*H_;   // transposed [H_][N_] (pre-scaled)
    float* Umat   = ws + o; o += (size_t)N_*H_;   // [N_][H_]   (pre-scaled)
    float* negv2  = ws + o; o += 256;
    float* sumv   = ws + o; o += 64;
    float* hglob  = ws + o; o += 512;             // double-buffered h [2][256]
    unsigned* cnt = (unsigned*)(ws + o); o += 64;
    int* pos      = (int*)(ws + o); o += N_;

    init_misc  <<<16, 256, 0, stream>>>(tour, attv, out + (size_t)N_*N_, pos, cnt, negv2, sumv);
    pos_scatter<<<16, 256, 0, stream>>>(tour, pos);
    embed2     <<<N_, 256, 0, stream>>>(x, eW, eb, cW, cb, emb, city);
    gather_dec <<<N_, 128, 0, stream>>>(city, st, tour, dseq);
    gemm64<<<dim3(G4_/64, N_/64), 256, 0, stream>>>(emb,  enc_Wih, exih, N_, G4_, E_, enc_bih, enc_bhh, 1.f, 0);
    gemm64<<<dim3(G4_/64, N_/64), 256, 0, stream>>>(dseq, dec_Wih, dxih, N_, G4_, E_, dec_bih, dec_bhh, 1.f, 0);
    lstm_scan<<<4, 256, 0, stream>>>(exih, enc_Whh, dxih, dec_Whh, encout, hx, hglob, cnt);
    gemm64<<<dim3(H_/64, N_/64), 256, 0, stream>>>(encout, W1, projT, N_, H_, H_, nullptr, nullptr, SCALE_T, 1);
    gemm64<<<dim3(H_/64, N_/64), 256, 0, stream>>>(hx,     W2, Umat,  N_, H_, H_, nullptr, nullptr, SCALE_T, 0);
    attn_scores<<<dim3(N_/TI_, N_/TT_), 256, 0, stream>>>(projT, Umat, negv2, sumv, pos, out);
    logsm<<<N_, 256, 0, stream>>>(out);
}

// Round 3
// 14454.669 us; speedup vs baseline: 2.5504x; 2.5504x over previous
//
#include <hip/hip_runtime.h>
#include <math.h>

#define N_   4096
#define E_   128
#define H_   256
#define G4_  1024
#define SCALE_T 2.8853900817779268f   // 2*log2(e): exp2(S*x) = e^(2x)
#define L2E_    1.4426950408889634f   // log2(e)
#define NEG_BIG -1.0e30f              // finite stand-in for -inf (harness: inf-inf -> NaN)
#define SENT_U  0x7FC00001u           // qNaN sentinel: h is always finite

__device__ __forceinline__ float sigm_fast(float x) {
    return __builtin_amdgcn_rcpf(1.f + __builtin_amdgcn_exp2f(-L2E_ * x));
}
__device__ __forceinline__ float tanh_fast(float x) {
    return 1.f - 2.f * __builtin_amdgcn_rcpf(1.f + __builtin_amdgcn_exp2f(SCALE_T * x));
}

// ---------------------------------------------------------------------------
// init: pos[i]=INF, tour tail of d_out, zero256, negv2[d]=-2*v[d], sumv=sum(v)
// ---------------------------------------------------------------------------
__global__ __launch_bounds__(256) void init_misc(
    const int* __restrict__ tour, const float* __restrict__ v,
    float* __restrict__ out_tail, int* __restrict__ pos,
    float* __restrict__ zero256, float* __restrict__ negv2, float* __restrict__ sumv)
{
    const int i = blockIdx.x * 256 + threadIdx.x;
    if (i < N_) {
        pos[i] = 0x7FFFFFFF;
        out_tail[i] = (float)tour[i];
    }
    if (blockIdx.x == 0) {
        __shared__ float red[256];
        const float vv = v[threadIdx.x];
        negv2[threadIdx.x] = -2.f * vv;
        zero256[threadIdx.x] = 0.f;
        red[threadIdx.x] = vv;
        __syncthreads();
        for (int s = 128; s > 0; s >>= 1) {
            if (threadIdx.x < s) red[threadIdx.x] += red[threadIdx.x + s];
            __syncthreads();
        }
        if (threadIdx.x == 0) sumv[0] = red[0];
    }
}

// sentinel-fill encout & hx (each N_*H_ floats) with qNaN pattern
__global__ __launch_bounds__(256) void fill_sent(uint4* __restrict__ a, uint4* __restrict__ b)
{
    const int i = blockIdx.x * 256 + threadIdx.x;   // 1024*256 = 262144 = N_*H_/4
    const uint4 s = make_uint4(SENT_U, SENT_U, SENT_U, SENT_U);
    a[i] = s;
    b[i] = s;
}

__global__ __launch_bounds__(256) void pos_scatter(
    const int* __restrict__ tour, int* __restrict__ pos)
{
    const int i = blockIdx.x * 256 + threadIdx.x;
    if (i < N_) atomicMin(&pos[tour[i]], i);
}

// ---------------------------------------------------------------------------
// embeddings: K=2 matvec, emb = x@eW.T+eb ; city = x@cW.T+cb
// ---------------------------------------------------------------------------
__global__ __launch_bounds__(256) void embed2(
    const float* __restrict__ x,
    const float* __restrict__ eW, const float* __restrict__ eb,
    const float* __restrict__ cW, const float* __restrict__ cb,
    float* __restrict__ emb, float* __restrict__ city)
{
    const int m = blockIdx.x, tid = threadIdx.x;
    const float x0 = x[2*m], x1 = x[2*m+1];
    if (tid < E_) {
        emb[(size_t)m*E_ + tid] = x0*eW[2*tid] + x1*eW[2*tid+1] + eb[tid];
    } else {
        const int e = tid - E_;
        city[(size_t)m*E_ + e] = x0*cW[2*e] + x1*cW[2*e+1] + cb[e];
    }
}

// dec_seq[0]=start_token ; dec_seq[t]=city_embs[tour[t-1]]
__global__ __launch_bounds__(128) void gather_dec(
    const float* __restrict__ city, const float* __restrict__ st,
    const int* __restrict__ tour, float* __restrict__ dseq)
{
    const int t = blockIdx.x, e = threadIdx.x;
    dseq[(size_t)t*E_ + e] = (t == 0) ? st[e] : city[(size_t)tour[t-1]*E_ + e];
}

// ---------------------------------------------------------------------------
// generic fp32 GEMM: C[M,N] = scale*(A[M,K] @ B[N,K]^T) (+b0[n]) (+b1[n])
// storeT: write C transposed as C[n*M+m] (used for projT)
// ---------------------------------------------------------------------------
__global__ __launch_bounds__(256) void gemm64(
    const float* __restrict__ A, const float* __restrict__ B, float* __restrict__ C,
    int M, int N, int K, const float* __restrict__ b0, const float* __restrict__ b1,
    float scale, int storeT)
{
    __shared__ float As[16][68];
    __shared__ float Bs[16][68];
    const int tid = threadIdx.x;
    const int m0 = blockIdx.y * 64, n0 = blockIdx.x * 64;
    const int tx = tid & 15, ty = tid >> 4;
    const int lr = tid >> 2, lk = (tid & 3) * 4;
    float acc[4][4] = {};
    for (int kb = 0; kb < K; kb += 16) {
        const float4 a4 = *(const float4*)&A[(size_t)(m0+lr)*K + kb + lk];
        const float4 b4 = *(const float4*)&B[(size_t)(n0+lr)*K + kb + lk];
        __syncthreads();
        As[lk][lr]=a4.x; As[lk+1][lr]=a4.y; As[lk+2][lr]=a4.z; As[lk+3][lr]=a4.w;
        Bs[lk][lr]=b4.x; Bs[lk+1][lr]=b4.y; Bs[lk+2][lr]=b4.z; Bs[lk+3][lr]=b4.w;
        __syncthreads();
        #pragma unroll
        for (int k = 0; k < 16; ++k) {
            const float4 av4 = *(const float4*)&As[k][ty*4];
            const float4 bv4 = *(const float4*)&Bs[k][tx*4];
            const float avv[4] = {av4.x, av4.y, av4.z, av4.w};
            const float bvv[4] = {bv4.x, bv4.y, bv4.z, bv4.w};
            #pragma unroll
            for (int i = 0; i < 4; ++i)
                #pragma unroll
                for (int j = 0; j < 4; ++j)
                    acc[i][j] += avv[i] * bvv[j];
        }
    }
    #pragma unroll
    for (int i = 0; i < 4; ++i) {
        const int m = m0 + ty*4 + i;
        #pragma unroll
        for (int j = 0; j < 4; ++j) {
            const int n = n0 + tx*4 + j;
            float val = scale * acc[i][j];
            if (b0) val += b0[n];
            if (b1) val += b1[n];
            if (storeT) C[(size_t)n*M + m] = val;
            else        C[(size_t)m*N + n] = val;
        }
    }
}

// ---------------------------------------------------------------------------
// LSTM scan v2: 4 WGs x 512 thr, data-spin on sentinel-filled h history.
// Thread (kh, r): gate row (r>>6)*256 + g*64 + (r&63), k-half kh.
// 128 fp32 weights register-resident per thread (no spill). No counter, no
// fence: readers poll h[s-1] words directly until != qNaN sentinel.
// ---------------------------------------------------------------------------
__device__ __forceinline__ void load_w128(const float* __restrict__ whh, int row, int kh,
                                          float (&w)[128])
{
    #pragma unroll
    for (int k = 0; k < 128; k += 4) {
        const float4 f = *(const float4*)&whh[(size_t)row*256 + kh*128 + k];
        w[k] = f.x; w[k+1] = f.y; w[k+2] = f.z; w[k+3] = f.w;
    }
}

__device__ __forceinline__ void scan_phase2(
    const float* __restrict__ xih, float* __restrict__ outbuf,
    const float* __restrict__ prev, const float (&w)[128], float& c_loc,
    float* __restrict__ hs, float* __restrict__ psum, float* __restrict__ actb,
    int t, int kh, int r, int q, int l, int g)
{
    const int row = q*256 + g*64 + l;
    for (int s = 0; s < N_; ++s) {
        float xv = 0.f;
        if (kh == 0) xv = xih[(size_t)s*G4_ + row];     // hidden under the spin
        const float* hsrc = (s == 0) ? prev : (outbuf + (size_t)(s-1)*H_);
        if (t < H_) {
            const unsigned* p = (const unsigned*)hsrc + t;
            unsigned uv = __hip_atomic_load(p, __ATOMIC_RELAXED, __HIP_MEMORY_SCOPE_AGENT);
            while (uv == SENT_U)
                uv = __hip_atomic_load(p, __ATOMIC_RELAXED, __HIP_MEMORY_SCOPE_AGENT);
            ((unsigned*)hs)[t] = uv;
        }
        __syncthreads();
        float a0 = 0.f, a1 = 0.f, a2 = 0.f, a3 = 0.f;
        const float* hk = &hs[kh*128];
        #pragma unroll
        for (int k = 0; k < 128; k += 4) {
            const float4 hv = *(const float4*)&hk[k];
            a0 += w[k]   * hv.x;
            a1 += w[k+1] * hv.y;
            a2 += w[k+2] * hv.z;
            a3 += w[k+3] * hv.w;
        }
        psum[t] = xv + (a0 + a1) + (a2 + a3);
        __syncthreads();
        if (kh == 0) {
            const float gate = psum[r] + psum[H_ + r];
            actb[r] = (q == 2) ? tanh_fast(gate) : sigm_fast(gate);
        }
        __syncthreads();
        if (t < 64) {
            const float iv = actb[t], fv = actb[64+t], gg = actb[128+t], ov = actb[192+t];
            c_loc = fv * c_loc + iv * gg;
            const float hn = ov * tanh_fast(c_loc);
            __hip_atomic_store(&outbuf[(size_t)s*H_ + g*64 + t], hn,
                               __ATOMIC_RELAXED, __HIP_MEMORY_SCOPE_AGENT);
        }
        // no end-of-loop barrier needed: actb(s) reads happen before sync1(s+1),
        // and actb(s+1) writes happen after sync2(s+1).
    }
}

__global__ __launch_bounds__(512, 1) void lstm_scan2(
    const float* __restrict__ exih, const float* __restrict__ ewhh,
    const float* __restrict__ dxih, const float* __restrict__ dwhh,
    const float* __restrict__ zero256,
    float* __restrict__ encout, float* __restrict__ hx)
{
    __shared__ __align__(16) float hs[H_];
    __shared__ float psum[512];
    __shared__ float actb[H_];
    const int g = blockIdx.x, t = threadIdx.x;
    const int kh = t >> 8;        // k-half
    const int r  = t & 255;       // gate-row local
    const int q  = r >> 6, l = r & 63;
    const int row = q*256 + g*64 + l;
    float w[128];
    load_w128(ewhh, row, kh, w);
    float c_loc = 0.f;
    scan_phase2(exih, encout, zero256,              w, c_loc, hs, psum, actb, t, kh, r, q, l, g);
    load_w128(dwhh, row, kh, w);
    scan_phase2(dxih, hx,     encout + (size_t)(N_-1)*H_, w, c_loc, hs, psum, actb, t, kh, r, q, l, g);
}

// ---------------------------------------------------------------------------
// attention scores: e[t][i] = sumv + sum_d negv2[d] * rcp(1 + exp2(p'+u'))
// (p', u' pre-scaled by 2*log2(e), so this is sum_d v_d * tanh(p+u))
// tile: 16 t x 32 i, block-skip when all i masked for whole tile
// ---------------------------------------------------------------------------
#define TI_ 32
#define TT_ 16

__global__ __launch_bounds__(256) void attn_scores(
    const float* __restrict__ projT, const float* __restrict__ Umat,
    const float* __restrict__ negv2, const float* __restrict__ sumvp,
    const int* __restrict__ pos, float* __restrict__ out)
{
    const int i0 = blockIdx.x * TI_, t0 = blockIdx.y * TT_;
    const int tid = threadIdx.x;
    const int lane = tid & 63, wv = tid >> 6;
    const int il = lane & 31, th = lane >> 5;
    const int pi = pos[i0 + il];
    if (__all(pi < t0)) {                   // entire tile masked -> NEG_BIG
        for (int idx = tid; idx < TT_*TI_; idx += 256) {
            const int r = idx >> 5, c = idx & 31;
            out[(size_t)(t0 + r)*N_ + i0 + c] = NEG_BIG;
        }
        return;
    }
    __shared__ float pTs[256][33];
    __shared__ float Us[TT_][256];
    __shared__ float vsh[256];
    vsh[tid] = negv2[tid];
    #pragma unroll
    for (int dd = 0; dd < 8; ++dd) {
        const int d = (tid >> 3) + dd*32;
        const float4 p4 = *(const float4*)&projT[(size_t)d*N_ + i0 + (tid & 7)*4];
        const int c = (tid & 7)*4;
        pTs[d][c] = p4.x; pTs[d][c+1] = p4.y; pTs[d][c+2] = p4.z; pTs[d][c+3] = p4.w;
    }
    for (int idx = tid; idx < TT_*256; idx += 256) {
        const int r = idx >> 8, c = idx & 255;
        Us[r][c] = Umat[(size_t)(t0 + r)*H_ + c];
    }
    __syncthreads();
    const float sumv = sumvp[0];
    #pragma unroll
    for (int pass = 0; pass < 2; ++pass) {
        const int tl = pass*8 + wv*2 + th;
        const int t = t0 + tl;
        float a0 = 0.f, a1 = 0.f, a2 = 0.f, a3 = 0.f;
        #pragma unroll 8
        for (int d = 0; d < 256; d += 4) {
            const float x0 = pTs[d  ][il] + Us[tl][d  ];
            const float x1 = pTs[d+1][il] + Us[tl][d+1];
            const float x2 = pTs[d+2][il] + Us[tl][d+2];
            const float x3 = pTs[d+3][il] + Us[tl][d+3];
            a0 += vsh[d  ] * __builtin_amdgcn_rcpf(1.f + exp2f(x0));
            a1 += vsh[d+1] * __builtin_amdgcn_rcpf(1.f + exp2f(x1));
            a2 += vsh[d+2] * __builtin_amdgcn_rcpf(1.f + exp2f(x2));
            a3 += vsh[d+3] * __builtin_amdgcn_rcpf(1.f + exp2f(x3));
        }
        float val = sumv + ((a0 + a1) + (a2 + a3));
        if (pi < t) val = NEG_BIG;
        out[(size_t)t*N_ + i0 + il] = val;
    }
}

// in-place row log_softmax over d_out rows (4096 elems each)
// masked entries are NEG_BIG; NEG_BIG - lse stays NEG_BIG (fp32), exp(NEG_BIG-m)=0
__global__ __launch_bounds__(256) void logsm(float* __restrict__ out)
{
    const int t = blockIdx.x, tid = threadIdx.x;
    float* row = out + (size_t)t*N_;
    float v[16];
    float lmax = NEG_BIG;
    #pragma unroll
    for (int j = 0; j < 16; ++j) { v[j] = row[tid + j*256]; lmax = fmaxf(lmax, v[j]); }
    __shared__ float red[256];
    red[tid] = lmax; __syncthreads();
    for (int s = 128; s > 0; s >>= 1) {
        if (tid < s) red[tid] = fmaxf(red[tid], red[tid + s]);
        __syncthreads();
    }
    const float m = red[0];
    __syncthreads();
    float lsum = 0.f;
    #pragma unroll
    for (int j = 0; j < 16; ++j) lsum += __expf(v[j] - m);
    red[tid] = lsum; __syncthreads();
    for (int s = 128; s > 0; s >>= 1) {
        if (tid < s) red[tid] += red[tid + s];
        __syncthreads();
    }
    const float lse = m + logf(red[0]);
    #pragma unroll
    for (int j = 0; j < 16; ++j) row[tid + j*256] = v[j] - lse;
}

// ---------------------------------------------------------------------------
extern "C" void kernel_launch(void* const* d_in, const int* in_sizes, int n_in,
                              void* d_out, int out_size, void* d_ws, size_t ws_size,
                              hipStream_t stream)
{
    const float* x        = (const float*)d_in[0];
    const int*   tour     = (const int*)  d_in[1];
    const float* eW       = (const float*)d_in[2];
    const float* eb       = (const float*)d_in[3];
    const float* enc_Wih  = (const float*)d_in[4];
    const float* enc_Whh  = (const float*)d_in[5];
    const float* enc_bih  = (const float*)d_in[6];
    const float* enc_bhh  = (const float*)d_in[7];
    const float* dec_Wih  = (const float*)d_in[8];
    const float* dec_Whh  = (const float*)d_in[9];
    const float* dec_bih  = (const float*)d_in[10];
    const float* dec_bhh  = (const float*)d_in[11];
    const float* W1       = (const float*)d_in[12];
    const float* W2       = (const float*)d_in[13];
    const float* attv     = (const float*)d_in[14];
    const float* cW       = (const float*)d_in[15];
    const float* cb       = (const float*)d_in[16];
    const float* st       = (const float*)d_in[17];
    float* out = (float*)d_out;

    float* ws = (float*)d_ws;
    size_t o = 0;
    float* emb    = ws + o; o += (size_t)N_*E_;
    float* city   = ws + o; o += (size_t)N_*E_;
    float* dseq   = ws + o; o += (size_t)N_*E_;
    float* exih   = ws + o; o += (size_t)N_*G4_;
    float* dxih   = ws + o; o += (size_t)N_*G4_;
    float* encout = ws + o; o += (size_t)N_*H_;
    float* hx     = ws + o; o += (size_t)N_*H_;
    float* projT  = ws + o; o += (size_t)N_*H_;   // transposed [H_][N_] (pre-scaled)
    float* Umat   = ws + o; o += (size_t)N_*H_;   // [N_][H_]   (pre-scaled)
    float* negv2  = ws + o; o += 256;
    float* sumv   = ws + o; o += 64;
    float* zero256= ws + o; o += 256;
    int* pos      = (int*)(ws + o); o += N_;

    init_misc  <<<16, 256, 0, stream>>>(tour, attv, out + (size_t)N_*N_, pos, zero256, negv2, sumv);
    fill_sent  <<<1024, 256, 0, stream>>>((uint4*)encout, (uint4*)hx);
    pos_scatter<<<16, 256, 0, stream>>>(tour, pos);
    embed2     <<<N_, 256, 0, stream>>>(x, eW, eb, cW, cb, emb, city);
    gather_dec <<<N_, 128, 0, stream>>>(city, st, tour, dseq);
    gemm64<<<dim3(G4_/64, N_/64), 256, 0, stream>>>(emb,  enc_Wih, exih, N_, G4_, E_, enc_bih, enc_bhh, 1.f, 0);
    gemm64<<<dim3(G4_/64, N_/64), 256, 0, stream>>>(dseq, dec_Wih, dxih, N_, G4_, E_, dec_bih, dec_bhh, 1.f, 0);
    lstm_scan2<<<4, 512, 0, stream>>>(exih, enc_Whh, dxih, dec_Whh, zero256, encout, hx);
    gemm64<<<dim3(H_/64, N_/64), 256, 0, stream>>>(encout, W1, projT, N_, H_, H_, nullptr, nullptr, SCALE_T, 1);
    gemm64<<<dim3(H_/64, N_/64), 256, 0, stream>>>(hx,     W2, Umat,  N_, H_, H_, nullptr, nullptr, SCALE_T, 0);
    attn_scores<<<dim3(N_/TI_, N_/TT_), 256, 0, stream>>>(projT, Umat, negv2, sumv, pos, out);
    logsm<<<N_, 256, 0, stream>>>(out);
}